// Round 1
// baseline (208.590 us; speedup 1.0000x reference)
//
#include <hip/hip_runtime.h>
#include <math.h>

#define NN     512     // N (columns of x)
#define KK     513     // K
#define BB     65536   // batch
#define TROWS  512     // table rows, t = 0..511
#define TCOLS  513     // table cols, g = 0..512

// T[t][g][c]:
//   t == 0                      -> 0 (step t=0 has no W term)
//   1 <= g <= t                 -> log softmax(W[t-1][g-1])[c]
//   g == 0 or g == t+1 (edges)  -> log(1) = 0
//   anything else               -> unreachable, set 0
__global__ void build_table_kernel(const float* __restrict__ W, float* __restrict__ T) {
    int idx = blockIdx.x * blockDim.x + threadIdx.x;
    if (idx >= TROWS * TCOLS) return;
    int t = idx / TCOLS;
    int g = idx - t * TCOLS;
    float v0 = 0.f, v1 = 0.f;
    if (t >= 1 && g >= 1 && g <= t) {
        const float* w = W + ((size_t)(t - 1) * (KK - 1) + (g - 1)) * 2;
        float w0 = w[0], w1 = w[1];
        float m  = fmaxf(w0, w1);
        float lse = m + logf(expf(w0 - m) + expf(w1 - m));
        v0 = w0 - lse;
        v1 = w1 - lse;
    }
    T[2 * idx + 0] = v0;
    T[2 * idx + 1] = v1;
}

// logE[k] = endW[k] - logsumexp(endW)   (513 entries), one wave
__global__ void build_endw_kernel(const float* __restrict__ endW, float* __restrict__ logE) {
    int lane = threadIdx.x;  // 0..63
    float vals[9];
    float m = -1e30f;
    #pragma unroll
    for (int k = 0; k < 9; ++k) {
        int i = lane + 64 * k;
        vals[k] = (i < KK) ? endW[i] : -1e30f;
        m = fmaxf(m, vals[k]);
    }
    #pragma unroll
    for (int d = 32; d >= 1; d >>= 1) m = fmaxf(m, __shfl_xor(m, d, 64));
    float s = 0.f;
    #pragma unroll
    for (int k = 0; k < 9; ++k) s += expf(vals[k] - m);  // -1e30 pads underflow to 0
    #pragma unroll
    for (int d = 32; d >= 1; d >>= 1) s += __shfl_xor(s, d, 64);
    float lse = m + logf(s);
    #pragma unroll
    for (int k = 0; k < 9; ++k) {
        int i = lane + 64 * k;
        if (i < KK) logE[i] = endW[i] - lse;
    }
}

// One thread per batch row. Lanes of a wave are 64 different rows, but lockstep
// execution means each gather instruction touches ONE table row t with
// binomially-concentrated g -> small, L1-resident hot set.
// x is read as int4 (16B) per 4 columns; next 16-column chunk (one 64B line)
// is prefetched while the current chunk computes.
__global__ __launch_bounds__(256) void pc_main_kernel(
    const int* __restrict__ x, const float* __restrict__ T,
    const float* __restrict__ logE, float* __restrict__ out)
{
    const int row = blockIdx.x * blockDim.x + threadIdx.x;
    if (row >= BB) return;
    const int4* xp = (const int4*)(x + (size_t)row * NN);

    float a0 = 0.f, a1 = 0.f, a2 = 0.f, a3 = 0.f;
    int g = 0;

    int4 c0 = xp[0], c1 = xp[1], c2 = xp[2], c3 = xp[3];

    for (int ch = 0; ch < 32; ++ch) {
        int4 n0 = make_int4(0, 0, 0, 0), n1 = n0, n2 = n0, n3 = n0;
        if (ch < 31) {
            const int4* p = xp + (ch + 1) * 4;
            n0 = p[0]; n1 = p[1]; n2 = p[2]; n3 = p[3];
        }
        const int xs[16] = { c0.x, c0.y, c0.z, c0.w,
                             c1.x, c1.y, c1.z, c1.w,
                             c2.x, c2.y, c2.z, c2.w,
                             c3.x, c3.y, c3.z, c3.w };
        const int tb = ch * 16;
        #pragma unroll
        for (int k = 0; k < 16; ++k) {
            g += xs[k];
            const float v = T[((tb + k) * TCOLS + g) * 2 + xs[k]];
            if      ((k & 3) == 0) a0 += v;
            else if ((k & 3) == 1) a1 += v;
            else if ((k & 3) == 2) a2 += v;
            else                   a3 += v;
        }
        c0 = n0; c1 = n1; c2 = n2; c3 = n3;
    }
    out[row] = (a0 + a1) + (a2 + a3) + logE[g];
}

extern "C" void kernel_launch(void* const* d_in, const int* in_sizes, int n_in,
                              void* d_out, int out_size, void* d_ws, size_t ws_size,
                              hipStream_t stream)
{
    const int*   x    = (const int*)d_in[0];
    const float* W    = (const float*)d_in[1];
    const float* endW = (const float*)d_in[2];
    float*       out  = (float*)d_out;

    float* T    = (float*)d_ws;                                   // 512*513*2 f32 = 2,101,248 B
    float* logE = (float*)((char*)d_ws + (size_t)TROWS * TCOLS * 2 * sizeof(float));

    {
        int total  = TROWS * TCOLS;
        int blocks = (total + 255) / 256;
        build_table_kernel<<<blocks, 256, 0, stream>>>(W, T);
    }
    build_endw_kernel<<<1, 64, 0, stream>>>(endW, logE);
    pc_main_kernel<<<BB / 256, 256, 0, stream>>>(x, T, logE, out);
}